// Round 10
// baseline (150.408 us; speedup 1.0000x reference)
//
#include <hip/hip_runtime.h>

#define B 256
#define N 512
#define M 512
#define BM (B * M)   // 131072
#define NM (N * M)   // 262144

// ===========================================================================
// Single fused kernel, 256 blocks x 512 threads (1 block/CU -> co-residency
// guaranteed for the software grid barrier).
//  Phase 1a (blocks 0..129): transpose tiles (x->xT, w->wT, t->tT) + f64 sums
//  Phase 1b (all blocks):    2 relx tiles each: px[z][m][n] (bit-identical)
//  Barrier: memset-zeroed counter, agent-scope fence + atomicAdd + spin
//  Phase 2 (all blocks):     k_col logic (R9-verbatim) for columns 2b, 2b+1
// ===========================================================================

__device__ __forceinline__ void tile_tr512(const float* __restrict__ src,
                                           float* __restrict__ dst,
                                           int R, int C, int r0, int c0, int tid) {
    __shared__ float s[64][65];
    const int tx = tid & 63, q = tid >> 6;   // 8 rows each
    #pragma unroll
    for (int j = 0; j < 8; ++j) {
        int rl = q * 8 + j;
        s[rl][tx] = src[(r0 + rl) * C + c0 + tx];
    }
    __syncthreads();
    #pragma unroll
    for (int j = 0; j < 8; ++j) {
        int cl = q * 8 + j;
        dst[(c0 + cl) * R + r0 + tx] = s[tx][cl];
    }
}

__global__ __launch_bounds__(512) void k_fused(
        const float* __restrict__ x, const float* __restrict__ w,
        const float* __restrict__ t, float* __restrict__ xT,
        float* __restrict__ wT, float* __restrict__ tT,
        float* __restrict__ sum_x, float* __restrict__ sum_w,
        float* __restrict__ px, int* __restrict__ bar,
        float* __restrict__ out) {
    const int blk = blockIdx.x, tid = threadIdx.x;
    const int lane = tid & 63, wid = tid >> 6;

    // ---- LDS: relx staging ----
    __shared__ float s_t[32][64];    // [b-local][m-local]; reused as 64x32 out
    __shared__ float s_x[32][36];    // [b-local][n-local]+pad
    // ---- LDS: k_col set (R9) ----
    __shared__ float  worig[512], pm[512], wsrt[512];
    __shared__ float  srx_r[512], srx_u[512];
    __shared__ int    srx_n[512];
    __shared__ int    cnt[256], cbase[256], cslot[256];
    __shared__ int    rcnt[256], rbase[256], rslot[256], rbmax[256];
    __shared__ double bsumI[256];
    __shared__ float  wtotmax[8], red3[3][8];
    __shared__ int    ctot[4], rtot[4];
    __shared__ double btot[4];

    // ================= Phase 1a: transposes + sums =================
    if (blk < 32) {
        tile_tr512(x, xT, B, N, (blk >> 3) * 64, (blk & 7) * 64, tid);
    } else if (blk < 96) {
        int id = blk - 32;
        tile_tr512(w, wT, N, M, (id >> 3) * 64, (id & 7) * 64, tid);
    } else if (blk < 128) {
        int id = blk - 96;
        tile_tr512(t, tT, B, M, (id >> 3) * 64, (id & 7) * 64, tid);
    } else if (blk == 128) {
        const int i = tid;                          // 512 elems, 1/thread
        double a0 = 0, a1 = 0, a2 = 0, a3 = 0;
        for (int b = 0; b < B; b += 4) {
            a0 += (double)x[(b + 0) * N + i];
            a1 += (double)x[(b + 1) * N + i];
            a2 += (double)x[(b + 2) * N + i];
            a3 += (double)x[(b + 3) * N + i];
        }
        sum_x[i] = (float)((a0 + a1) + (a2 + a3));
    } else if (blk == 129) {
        const int mm = tid;
        double a0 = 0, a1 = 0, a2 = 0, a3 = 0;
        for (int n = 0; n < N; n += 4) {
            a0 += (double)w[(n + 0) * M + mm];
            a1 += (double)w[(n + 1) * M + mm];
            a2 += (double)w[(n + 2) * M + mm];
            a3 += (double)w[(n + 3) * M + mm];
        }
        sum_w[mm] = (float)((a0 + a1) + (a2 + a3));
    }

    // ================= Phase 1b: 2 relx tiles per block =================
    // tile 64m x 32n; thread = 4m x 1n; per-cell b-order ascending (identical)
    const int tx = tid & 15;          // m-group: m_l = tx*4..+3
    const int ny = tid >> 4;          // n-local 0..31
    #pragma unroll 1
    for (int r = 0; r < 2; ++r) {
        const int id = blk * 2 + r;                  // 0..511
        const int z   = id >> 7;
        const int rem = id & 127;
        const int m0 = (rem & 7) * 64;
        const int n0 = (rem >> 3) * 32;
        float a0 = 0.f, a1 = 0.f, a2 = 0.f, a3 = 0.f;
        for (int scnk = 0; scnk < 2; ++scnk) {
            const int bb = z * 64 + scnk * 32;
            __syncthreads();
            { int sr = tid >> 4, sc = (tid & 15) * 4;
              *(float4*)&s_t[sr][sc] = *(const float4*)&t[(bb + sr) * M + m0 + sc]; }
            if (tid < 256) {
                int sr2 = tid >> 3, sc2 = (tid & 7) * 4;
                *(float4*)&s_x[sr2][sc2] = *(const float4*)&x[(bb + sr2) * N + n0 + sc2];
            }
            __syncthreads();
            #pragma unroll 8
            for (int i = 0; i < 32; ++i) {           // ascending b: bit-identical
                float4 tv = *(const float4*)&s_t[i][tx * 4];
                float xv = s_x[i][ny];
                a0 += fminf(xv, tv.x); a1 += fminf(xv, tv.y);
                a2 += fminf(xv, tv.z); a3 += fminf(xv, tv.w);
            }
        }
        __syncthreads();
        float* so = &s_t[0][0];                      // 64x32 restage
        so[(tx * 4 + 0) * 32 + ny] = a0;
        so[(tx * 4 + 1) * 32 + ny] = a1;
        so[(tx * 4 + 2) * 32 + ny] = a2;
        so[(tx * 4 + 3) * 32 + ny] = a3;
        __syncthreads();
        const int m_l = tid >> 3, n_l4 = (tid & 7) * 4;
        *(float4*)&px[z * NM + (m0 + m_l) * N + n0 + n_l4] =
            *(const float4*)&so[m_l * 32 + n_l4];
    }

    // ================= Grid barrier (counter memset to 0 by host) ==========
    __syncthreads();                                  // drains all vm writes
    if (tid == 0) {
        __threadfence();                              // agent release (wb L2)
        atomicAdd(bar, 1);                            // device-scope
        while (__hip_atomic_load(bar, __ATOMIC_RELAXED, __HIP_MEMORY_SCOPE_AGENT) < 256) { }
    }
    __syncthreads();
    __threadfence();                                  // agent acquire (inv)

    // ================= Phase 2: k_col (R9-verbatim) for 2 columns ==========
    for (int mi = 0; mi < 2; ++mi) {
        const int m = blk * 2 + mi;
        __syncthreads();                              // protect LDS reuse

        const float wv = wT[m * N + tid];
        float p = px[m * N + tid];
        p += px[NM + m * N + tid];
        p += px[2 * NM + m * N + tid];
        p += px[3 * NM + m * N + tid];
        const float rv = p / sum_x[tid];
        worig[tid] = wv;
        if (tid < 256) { cnt[tid] = 0; rcnt[tid] = 0; cslot[tid] = 0; rslot[tid] = 0; rbmax[tid] = 0; }

        float pmv = wv;
        #pragma unroll
        for (int off = 1; off < 64; off <<= 1) {
            float o = __shfl_up(pmv, off, 64);
            if (lane >= off) pmv = fmaxf(pmv, o);
        }
        if (lane == 63) wtotmax[wid] = pmv;
        float wmn = wv, rmn = rv, rmx = rv;
        #pragma unroll
        for (int off = 32; off > 0; off >>= 1) {
            wmn = fminf(wmn, __shfl_xor(wmn, off, 64));
            rmn = fminf(rmn, __shfl_xor(rmn, off, 64));
            rmx = fmaxf(rmx, __shfl_xor(rmx, off, 64));
        }
        if (lane == 0) { red3[0][wid] = wmn; red3[1][wid] = rmn; red3[2][wid] = rmx; }
        __syncthreads();                                           // (1)

        {
            float om = -1e30f;
            for (int j = 0; j < wid; ++j) om = fmaxf(om, wtotmax[j]);
            pm[tid] = fmaxf(pmv, om);
        }
        float wmin = red3[0][0], rmin = red3[1][0], rmax = red3[2][0], wmax = wtotmax[0];
        #pragma unroll
        for (int j = 1; j < 8; ++j) {
            wmin = fminf(wmin, red3[0][j]);
            rmin = fminf(rmin, red3[1][j]);
            rmax = fmaxf(rmax, red3[2][j]);
            wmax = fmaxf(wmax, wtotmax[j]);
        }

        const float wscale = 255.0f / fmaxf(wmax - wmin, 1e-30f);
        int wk = (int)((wv - wmin) * wscale);
        wk = wk < 0 ? 0 : (wk > 255 ? 255 : wk);
        atomicAdd(&cnt[wk], 1);
        const float rscale = 255.0f / fmaxf(rmax - rmin, 1e-30f);
        int rk;
        { int kv = (int)((rv - rmin) * rscale); kv = kv < 0 ? 0 : (kv > 255 ? 255 : kv); rk = 255 - kv; }
        atomicAdd(&rcnt[rk], 1);
        atomicMax(&rbmax[rk], __float_as_int(rv));                 // rv > 0
        __syncthreads();                                           // (2)

        int myc = (tid < 256) ? cnt[tid] : rcnt[tid - 256];
        int incl = myc;
        #pragma unroll
        for (int off = 1; off < 64; off <<= 1) {
            int o = __shfl_up(incl, off, 64);
            if (lane >= off) incl += o;
        }
        if (lane == 63) { if (wid < 4) ctot[wid] = incl; else rtot[wid - 4] = incl; }
        __syncthreads();                                           // (3)
        if (tid < 256) {
            int eo = 0;
            for (int j = 0; j < wid; ++j) eo += ctot[j];
            cbase[tid] = eo + incl - myc;
        } else {
            int eo = 0, w2 = wid - 4;
            for (int j = 0; j < w2; ++j) eo += rtot[j];
            rbase[tid - 256] = eo + incl - myc;
        }
        __syncthreads();                                           // (4)

        { int p1 = cbase[wk] + atomicAdd(&cslot[wk], 1); wsrt[p1] = wv; }
        { int p2 = rbase[rk] + atomicAdd(&rslot[rk], 1);
          srx_r[p2] = rv; srx_n[p2] = tid; srx_u[p2] = __int_as_float(rbmax[rk]); }
        __syncthreads();                                           // (5)

        double bincl = 0.0, mysum = 0.0;
        if (tid < 256) {
            int st = cbase[tid], e = st + cnt[tid];
            for (int i = st; i < e; ++i) mysum += (double)wsrt[i];
            bincl = mysum;
            #pragma unroll
            for (int off = 1; off < 64; off <<= 1) {
                double o = __shfl_up(bincl, off, 64);
                if (lane >= off) bincl += o;
            }
            if (lane == 63) btot[wid] = bincl;
        }
        __syncthreads();                                           // (6)
        if (tid < 256) {
            double eo = 0.0;
            for (int j = 0; j < wid; ++j) eo += btot[j];
            bsumI[tid] = eo + bincl;
        }
        __syncthreads();                                           // (7)

        if (tid < 256) {
            // ==== phase C: ind_w scan, descending-rel buckets ====
            const int b = tid;
            float bv = -1.0f; int bi = 0;
            for (int i = 0; i < 512; ++i) {
                float u = srx_u[i];                  // non-increasing bound
                if (__ballot(u >= bv) == 0ULL) break;
                float r = srx_r[i];
                int   n = srx_n[i];
                float xv = xT[n * B + b];            // coalesced
                float v = fminf(xv, r);
                if (v > bv || (v == bv && n < bi)) { bv = v; bi = n; }
            }
            out[BM + b * M + m] = fminf(x[b * N + bi], worig[bi]);   // chosen_w
        } else {
            // ==== phase D: rel_w CDF + ind_x ====
            const int b = tid - 256;
            const float tbm = tT[m * B + b];
            float btf = (tbm - wmin) * wscale;
            int kk; double S;
            if (btf < 0.0f) { kk = 0; S = 0.0; }
            else {
                int bt = (int)btf; bt = bt > 255 ? 255 : bt;
                kk = cbase[bt];
                S = (bt > 0) ? bsumI[bt - 1] : 0.0;
                int e = cbase[bt] + cnt[bt];
                for (int i = cbase[bt]; i < e; ++i) {
                    float v = wsrt[i];
                    if (v < tbm) { ++kk; S += (double)v; }
                }
            }
            double rw = S + (double)tbm * (double)(512 - kk);
            float c = (float)rw / sum_w[m];
            float tgt = fminf(c, pm[511]);
            int lo = 0, hi = 511;
            while (lo < hi) { int mid = (lo + hi) >> 1; if (pm[mid] >= tgt) hi = mid; else lo = mid + 1; }
            const int ind = lo;
            out[b * M + m] = fminf(x[b * N + ind], worig[ind]);      // chosen_x
        }
    }
}

extern "C" void kernel_launch(void* const* d_in, const int* in_sizes, int n_in,
                              void* d_out, int out_size, void* d_ws, size_t ws_size,
                              hipStream_t stream) {
    const float* x = (const float*)d_in[0];  // (B, N)
    const float* w = (const float*)d_in[1];  // (N, M)
    const float* t = (const float*)d_in[2];  // (B, M)
    float* out = (float*)d_out;

    float* ws = (float*)d_ws;
    float* xT    = ws;                 // 131072
    float* wT    = ws + 131072;        // 262144
    float* tT    = ws + 393216;        // 131072
    float* sum_x = ws + 524288;        // 512
    float* sum_w = ws + 524800;        // 512
    float* px    = ws + 525312;        // 4*NM = 1048576
    int*   bar   = (int*)(ws + 1573888);

    hipMemsetAsync(bar, 0, sizeof(int), stream);     // known-zero barrier base
    k_fused<<<256, 512, 0, stream>>>(x, w, t, xT, wT, tT, sum_x, sum_w, px, bar, out);
}

// Round 11
// 115.393 us; speedup vs baseline: 1.3034x; 1.3034x over previous
//
#include <hip/hip_runtime.h>

#define B 256
#define N 512
#define M 512
#define BM (B * M)   // 131072

// ===========================================================================
// k_a: 129 blocks x 256 threads: transposes + f64 sum_w.
//  blk 0..31: xT tiles   blk 32..95: wT tiles   blk 96..127: tT tiles
//  blk 128  : sum_w (2 elems/thread, per-element arithmetic identical to R9)
// ===========================================================================
__device__ __forceinline__ void tile_tr256(const float* __restrict__ src,
                                           float* __restrict__ dst,
                                           int R, int C, int r0, int c0, int tid) {
    __shared__ float s[64][65];
    const int tx = tid & 63, q = tid >> 6;
    #pragma unroll
    for (int j = 0; j < 16; ++j) {
        int rl = q * 16 + j;
        s[rl][tx] = src[(r0 + rl) * C + c0 + tx];
    }
    __syncthreads();
    #pragma unroll
    for (int j = 0; j < 16; ++j) {
        int cl = q * 16 + j;
        dst[(c0 + cl) * R + r0 + tx] = s[tx][cl];
    }
}

__global__ __launch_bounds__(256) void k_a(const float* __restrict__ x,
                                           const float* __restrict__ w,
                                           const float* __restrict__ t,
                                           float* __restrict__ xT,
                                           float* __restrict__ wT,
                                           float* __restrict__ tT,
                                           float* __restrict__ sum_w) {
    const int blk = blockIdx.x, tid = threadIdx.x;
    if (blk < 32) {
        tile_tr256(x, xT, B, N, (blk >> 3) * 64, (blk & 7) * 64, tid);
    } else if (blk < 96) {
        int id = blk - 32;
        tile_tr256(w, wT, N, M, (id >> 3) * 64, (id & 7) * 64, tid);
    } else if (blk < 128) {
        int id = blk - 96;
        tile_tr256(t, tT, B, M, (id >> 3) * 64, (id & 7) * 64, tid);
    } else {
        for (int mm = tid; mm < M; mm += 256) {
            double a0 = 0, a1 = 0, a2 = 0, a3 = 0;
            for (int n = 0; n < N; n += 4) {
                a0 += (double)w[(n + 0) * M + mm];
                a1 += (double)w[(n + 1) * M + mm];
                a2 += (double)w[(n + 2) * M + mm];
                a3 += (double)w[(n + 3) * M + mm];
            }
            sum_w[mm] = (float)((a0 + a1) + (a2 + a3));
        }
    }
}

// ===========================================================================
// k_col: one block per column m (512 x 512). Phase A computes the rel column
// in-block (bit-identical accumulation to R9's px path: 4 f32 chunk partials
// over b ascending, folded ((q0+q1)+q2)+q3; f64 sum_x with b&3 slots in
// k_sums' per-element order). Phases B-D identical to R9 (absmax 0 proven),
// with tT[m*B+b] served from the LDS t-column.
// ===========================================================================
__global__ __launch_bounds__(512) void k_col(
        const float* __restrict__ x, const float* __restrict__ xT,
        const float* __restrict__ wT, const float* __restrict__ tT,
        const float* __restrict__ sum_w, float* __restrict__ out) {
    const int m = blockIdx.x, tid = threadIdx.x;
    const int lane = tid & 63, wid = tid >> 6;

    __shared__ float  tcol[256];
    __shared__ float  worig[512], pm[512], wsrt[512];
    __shared__ float  srx_r[512], srx_u[512];
    __shared__ int    srx_n[512];
    __shared__ int    cnt[256], cbase[256], cslot[256];
    __shared__ int    rcnt[256], rbase[256], rslot[256], rbmax[256];
    __shared__ double bsumI[256];
    __shared__ float  wtotmax[8], red3[3][8];
    __shared__ int    ctot[4], rtot[4];
    __shared__ double btot[4];

    if (tid < 256) tcol[tid] = tT[m * B + tid];      // coalesced t column
    if (tid < 256) { cnt[tid] = 0; rcnt[tid] = 0; cslot[tid] = 0; rslot[tid] = 0; rbmax[tid] = 0; }
    __syncthreads();

    // ---- Phase A: rel value for n = tid (coalesced x reads, t broadcast) ----
    const float* xc = x + tid;                       // x[b*N + tid]
    float q0 = 0.f, q1 = 0.f, q2 = 0.f, q3 = 0.f;
    double a0 = 0, a1 = 0, a2 = 0, a3 = 0;
    #pragma unroll 1
    for (int z = 0; z < 4; ++z) {                    // chunk z: b in [64z,64z+64)
        float s = 0.f;
        #pragma unroll 4
        for (int b4 = z * 64; b4 < z * 64 + 64; b4 += 4) {
            float x0 = xc[(b4 + 0) * N], t0 = tcol[b4 + 0];
            float x1 = xc[(b4 + 1) * N], t1 = tcol[b4 + 1];
            float x2 = xc[(b4 + 2) * N], t2 = tcol[b4 + 2];
            float x3 = xc[(b4 + 3) * N], t3 = tcol[b4 + 3];
            s += fminf(x0, t0); s += fminf(x1, t1);  // ascending b: bit-identical
            s += fminf(x2, t2); s += fminf(x3, t3);
            a0 += (double)x0; a1 += (double)x1;      // k_sums slot pattern
            a2 += (double)x2; a3 += (double)x3;
        }
        if (z == 0) q0 = s; else if (z == 1) q1 = s; else if (z == 2) q2 = s; else q3 = s;
    }
    const float p = ((q0 + q1) + q2) + q3;
    const float sxf = (float)((a0 + a1) + (a2 + a3));
    const float rv = p / sxf;
    const float wv = wT[m * N + tid];
    worig[tid] = wv;

    // ---- wave prefix-max (pm) + wave reductions (wmin,rmin,rmax) ----
    float pmv = wv;
    #pragma unroll
    for (int off = 1; off < 64; off <<= 1) {
        float o = __shfl_up(pmv, off, 64);
        if (lane >= off) pmv = fmaxf(pmv, o);
    }
    if (lane == 63) wtotmax[wid] = pmv;
    float wmn = wv, rmn = rv, rmx = rv;
    #pragma unroll
    for (int off = 32; off > 0; off >>= 1) {
        wmn = fminf(wmn, __shfl_xor(wmn, off, 64));
        rmn = fminf(rmn, __shfl_xor(rmn, off, 64));
        rmx = fmaxf(rmx, __shfl_xor(rmx, off, 64));
    }
    if (lane == 0) { red3[0][wid] = wmn; red3[1][wid] = rmn; red3[2][wid] = rmx; }
    __syncthreads();                                           // (1)

    {
        float om = -1e30f;
        for (int j = 0; j < wid; ++j) om = fmaxf(om, wtotmax[j]);
        pm[tid] = fmaxf(pmv, om);
    }
    float wmin = red3[0][0], rmin = red3[1][0], rmax = red3[2][0], wmax = wtotmax[0];
    #pragma unroll
    for (int j = 1; j < 8; ++j) {
        wmin = fminf(wmin, red3[0][j]);
        rmin = fminf(rmin, red3[1][j]);
        rmax = fmaxf(rmax, red3[2][j]);
        wmax = fmaxf(wmax, wtotmax[j]);
    }

    // ---- histograms ----
    const float wscale = 255.0f / fmaxf(wmax - wmin, 1e-30f);
    int wk = (int)((wv - wmin) * wscale);
    wk = wk < 0 ? 0 : (wk > 255 ? 255 : wk);
    atomicAdd(&cnt[wk], 1);
    const float rscale = 255.0f / fmaxf(rmax - rmin, 1e-30f);
    int rk;
    { int kv = (int)((rv - rmin) * rscale); kv = kv < 0 ? 0 : (kv > 255 ? 255 : kv); rk = 255 - kv; }
    atomicAdd(&rcnt[rk], 1);
    atomicMax(&rbmax[rk], __float_as_int(rv));                 // rv > 0
    __syncthreads();                                           // (2)

    // ---- both 256-prefix-sums concurrently: waves 0-3 cnt, waves 4-7 rcnt ----
    int myc = (tid < 256) ? cnt[tid] : rcnt[tid - 256];
    int incl = myc;
    #pragma unroll
    for (int off = 1; off < 64; off <<= 1) {
        int o = __shfl_up(incl, off, 64);
        if (lane >= off) incl += o;
    }
    if (lane == 63) { if (wid < 4) ctot[wid] = incl; else rtot[wid - 4] = incl; }
    __syncthreads();                                           // (3)
    if (tid < 256) {
        int eo = 0;
        for (int j = 0; j < wid; ++j) eo += ctot[j];
        cbase[tid] = eo + incl - myc;
    } else {
        int eo = 0, w2 = wid - 4;
        for (int j = 0; j < w2; ++j) eo += rtot[j];
        rbase[tid - 256] = eo + incl - myc;
    }
    __syncthreads();                                           // (4)

    // ---- scatter (bucket-ordered) ----
    { int p1 = cbase[wk] + atomicAdd(&cslot[wk], 1); wsrt[p1] = wv; }
    { int p2 = rbase[rk] + atomicAdd(&rslot[rk], 1);
      srx_r[p2] = rv; srx_n[p2] = tid; srx_u[p2] = __int_as_float(rbmax[rk]); }
    __syncthreads();                                           // (5)

    // ---- per-bucket f64 sums + 256-prefix (waves 0-3) ----
    double bincl = 0.0, mysum = 0.0;
    if (tid < 256) {
        int st = cbase[tid], e = st + cnt[tid];
        for (int i = st; i < e; ++i) mysum += (double)wsrt[i];
        bincl = mysum;
        #pragma unroll
        for (int off = 1; off < 64; off <<= 1) {
            double o = __shfl_up(bincl, off, 64);
            if (lane >= off) bincl += o;
        }
        if (lane == 63) btot[wid] = bincl;
    }
    __syncthreads();                                           // (6)
    if (tid < 256) {
        double eo = 0.0;
        for (int j = 0; j < wid; ++j) eo += btot[j];
        bsumI[tid] = eo + bincl;
    }
    __syncthreads();                                           // (7)

    if (tid < 256) {
        // ==== phase C: ind_w scan, descending-rel buckets (waves 0-3) ====
        const int b = tid;
        float bv = -1.0f; int bi = 0;
        for (int i = 0; i < 512; ++i) {
            float u = srx_u[i];                      // non-increasing bound
            if (__ballot(u >= bv) == 0ULL) break;
            float r = srx_r[i];
            int   n = srx_n[i];
            float xv = xT[n * B + b];                // coalesced
            float v = fminf(xv, r);
            if (v > bv || (v == bv && n < bi)) { bv = v; bi = n; }
        }
        out[BM + b * M + m] = fminf(x[b * N + bi], worig[bi]);   // chosen_w
    } else {
        // ==== phase D: rel_w CDF + ind_x (waves 4-7) ====
        const int b = tid - 256;
        const float tbm = tcol[b];
        float btf = (tbm - wmin) * wscale;
        int kk; double S;
        if (btf < 0.0f) { kk = 0; S = 0.0; }
        else {
            int bt = (int)btf; bt = bt > 255 ? 255 : bt;
            kk = cbase[bt];
            S = (bt > 0) ? bsumI[bt - 1] : 0.0;
            int e = cbase[bt] + cnt[bt];
            for (int i = cbase[bt]; i < e; ++i) {
                float v = wsrt[i];
                if (v < tbm) { ++kk; S += (double)v; }
            }
        }
        double rw = S + (double)tbm * (double)(512 - kk);
        float c = (float)rw / sum_w[m];
        float tgt = fminf(c, pm[511]);
        int lo = 0, hi = 511;
        while (lo < hi) { int mid = (lo + hi) >> 1; if (pm[mid] >= tgt) hi = mid; else lo = mid + 1; }
        const int ind = lo;
        out[b * M + m] = fminf(x[b * N + ind], worig[ind]);      // chosen_x
    }
}

extern "C" void kernel_launch(void* const* d_in, const int* in_sizes, int n_in,
                              void* d_out, int out_size, void* d_ws, size_t ws_size,
                              hipStream_t stream) {
    const float* x = (const float*)d_in[0];  // (B, N)
    const float* w = (const float*)d_in[1];  // (N, M)
    const float* t = (const float*)d_in[2];  // (B, M)
    float* out = (float*)d_out;

    float* ws = (float*)d_ws;
    float* xT    = ws;                 // 131072
    float* wT    = ws + 131072;        // 262144
    float* tT    = ws + 393216;        // 131072
    float* sum_w = ws + 524288;        // 512   (~2.1 MB total)

    k_a  <<<129, 256, 0, stream>>>(x, w, t, xT, wT, tT, sum_w);
    k_col<<<512, 512, 0, stream>>>(x, xT, wT, tT, sum_w, out);
}

// Round 12
// 89.791 us; speedup vs baseline: 1.6751x; 1.2851x over previous
//
#include <hip/hip_runtime.h>

#define B 256
#define N 512
#define M 512
#define BM (B * M)   // 131072
#define NM (N * M)   // 262144

// ===========================================================================
// k_a: one launch, 644 blocks x 256 threads. Short blocks FIRST so the
// homogeneous relx blocks (not the serial sum tails) are the stragglers.
//  blk 0..31   : xT tiles    blk 32..95: wT tiles    blk 96..127: tT tiles
//  blk 128..129: sum_x (1 elem/thread, bit-identical per-element f64 order)
//  blk 130..131: sum_w (likewise)
//  blk 132..643: relxA tiles  px[z][m][n] = sum_{b in chunk z} min(x,t)
// ===========================================================================
__device__ __forceinline__ void tile_tr256(const float* __restrict__ src,
                                           float* __restrict__ dst,
                                           int R, int C, int r0, int c0, int tid) {
    __shared__ float s[64][65];
    const int tx = tid & 63, q = tid >> 6;
    #pragma unroll
    for (int j = 0; j < 16; ++j) {
        int rl = q * 16 + j;
        s[rl][tx] = src[(r0 + rl) * C + c0 + tx];
    }
    __syncthreads();
    #pragma unroll
    for (int j = 0; j < 16; ++j) {
        int cl = q * 16 + j;
        dst[(c0 + cl) * R + r0 + tx] = s[tx][cl];
    }
}

__global__ __launch_bounds__(256) void k_a(const float* __restrict__ x,
                                           const float* __restrict__ w,
                                           const float* __restrict__ t,
                                           float* __restrict__ xT,
                                           float* __restrict__ wT,
                                           float* __restrict__ tT,
                                           float* __restrict__ sum_x,
                                           float* __restrict__ sum_w,
                                           float* __restrict__ px) {
    const int blk = blockIdx.x, tid = threadIdx.x;
    if (blk < 32) {
        tile_tr256(x, xT, B, N, (blk >> 3) * 64, (blk & 7) * 64, tid);
    } else if (blk < 96) {
        int id = blk - 32;
        tile_tr256(w, wT, N, M, (id >> 3) * 64, (id & 7) * 64, tid);
    } else if (blk < 128) {
        int id = blk - 96;
        tile_tr256(t, tT, B, M, (id >> 3) * 64, (id & 7) * 64, tid);
    } else if (blk < 130) {
        const int i = (blk - 128) * 256 + tid;       // one element per thread
        double a0 = 0, a1 = 0, a2 = 0, a3 = 0;
        for (int b = 0; b < B; b += 4) {
            a0 += (double)x[(b + 0) * N + i];
            a1 += (double)x[(b + 1) * N + i];
            a2 += (double)x[(b + 2) * N + i];
            a3 += (double)x[(b + 3) * N + i];
        }
        sum_x[i] = (float)((a0 + a1) + (a2 + a3));
    } else if (blk < 132) {
        const int mm = (blk - 130) * 256 + tid;
        double a0 = 0, a1 = 0, a2 = 0, a3 = 0;
        for (int n = 0; n < N; n += 4) {
            a0 += (double)w[(n + 0) * M + mm];
            a1 += (double)w[(n + 1) * M + mm];
            a2 += (double)w[(n + 2) * M + mm];
            a3 += (double)w[(n + 3) * M + mm];
        }
        sum_w[mm] = (float)((a0 + a1) + (a2 + a3));
    } else {
        // ---- relxA: tile 64m x 32n, thread = 4m x 2n, z-chunk of 64 b ----
        const int rb  = blk - 132;
        const int z   = rb >> 7;
        const int rem = rb & 127;
        const int m0 = (rem & 7) * 64;
        const int n0 = (rem >> 3) * 32;
        const int tx = tid & 15, ty = tid >> 4;      // tx: m-group, ty: n-group
        __shared__ float s_t[32][64];                // [b-local][m-local]
        __shared__ float s_x[32][36];                // [b-local][n-local]+pad
        const int sr = tid >> 3, sc = tid & 7;
        float aA0 = 0.f, aA1 = 0.f, aA2 = 0.f, aA3 = 0.f;
        float aB0 = 0.f, aB1 = 0.f, aB2 = 0.f, aB3 = 0.f;
        const int nA = ty * 2, nB = nA + 1;
        for (int scnk = 0; scnk < 2; ++scnk) {
            const int bb = z * 64 + scnk * 32;
            __syncthreads();
            *(float4*)&s_t[sr][sc * 8]     = *(const float4*)&t[(bb + sr) * M + m0 + sc * 8];
            *(float4*)&s_t[sr][sc * 8 + 4] = *(const float4*)&t[(bb + sr) * M + m0 + sc * 8 + 4];
            *(float4*)&s_x[sr][sc * 4]     = *(const float4*)&x[(bb + sr) * N + n0 + sc * 4];
            __syncthreads();
            #pragma unroll 8
            for (int i = 0; i < 32; ++i) {           // b ascending: bit-identical
                float4 tv = *(const float4*)&s_t[i][tx * 4];
                float xA = s_x[i][nA], xB = s_x[i][nB];
                aA0 += fminf(xA, tv.x); aA1 += fminf(xA, tv.y);
                aA2 += fminf(xA, tv.z); aA3 += fminf(xA, tv.w);
                aB0 += fminf(xB, tv.x); aB1 += fminf(xB, tv.y);
                aB2 += fminf(xB, tv.z); aB3 += fminf(xB, tv.w);
            }
        }
        // stage 64x32 output tile in LDS (reuse s_t), store coalesced
        __syncthreads();
        float* so = &s_t[0][0];                      // [m-local*32 + n-local]
        so[(tx * 4 + 0) * 32 + nA] = aA0; so[(tx * 4 + 0) * 32 + nB] = aB0;
        so[(tx * 4 + 1) * 32 + nA] = aA1; so[(tx * 4 + 1) * 32 + nB] = aB1;
        so[(tx * 4 + 2) * 32 + nA] = aA2; so[(tx * 4 + 2) * 32 + nB] = aB2;
        so[(tx * 4 + 3) * 32 + nA] = aA3; so[(tx * 4 + 3) * 32 + nB] = aB3;
        __syncthreads();
        const int m_l = tid >> 2, n_l = (tid & 3) * 8;
        float* dst = &px[z * NM + (m0 + m_l) * N + n0 + n_l];
        *(float4*)&dst[0] = *(const float4*)&so[m_l * 32 + n_l];
        *(float4*)&dst[4] = *(const float4*)&so[m_l * 32 + n_l + 4];
    }
}

// ===========================================================================
// k_col: one block per column m (identical to R9, absmax 0 proven).
// ===========================================================================
__global__ __launch_bounds__(512) void k_col(
        const float* __restrict__ x, const float* __restrict__ xT,
        const float* __restrict__ wT, const float* __restrict__ tT,
        const float* __restrict__ px, const float* __restrict__ sum_x,
        const float* __restrict__ sum_w, float* __restrict__ out) {
    const int m = blockIdx.x, tid = threadIdx.x;
    const int lane = tid & 63, wid = tid >> 6;

    __shared__ float  worig[512], pm[512], wsrt[512];
    __shared__ float  srx_r[512], srx_u[512];
    __shared__ int    srx_n[512];
    __shared__ int    cnt[256], cbase[256], cslot[256];
    __shared__ int    rcnt[256], rbase[256], rslot[256], rbmax[256];
    __shared__ double bsumI[256];
    __shared__ float  wtotmax[8], red3[3][8];
    __shared__ int    ctot[4], rtot[4];
    __shared__ double btot[4];

    // ---- loads (bit-identical rv expression to R7/R8/R9) ----
    const float wv = wT[m * N + tid];
    float p = px[m * N + tid];
    p += px[NM + m * N + tid];
    p += px[2 * NM + m * N + tid];
    p += px[3 * NM + m * N + tid];
    const float rv = p / sum_x[tid];
    worig[tid] = wv;
    if (tid < 256) { cnt[tid] = 0; rcnt[tid] = 0; cslot[tid] = 0; rslot[tid] = 0; rbmax[tid] = 0; }

    // ---- wave prefix-max (pm) + wave reductions (wmin,rmin,rmax) ----
    float pmv = wv;
    #pragma unroll
    for (int off = 1; off < 64; off <<= 1) {
        float o = __shfl_up(pmv, off, 64);
        if (lane >= off) pmv = fmaxf(pmv, o);
    }
    if (lane == 63) wtotmax[wid] = pmv;
    float wmn = wv, rmn = rv, rmx = rv;
    #pragma unroll
    for (int off = 32; off > 0; off >>= 1) {
        wmn = fminf(wmn, __shfl_xor(wmn, off, 64));
        rmn = fminf(rmn, __shfl_xor(rmn, off, 64));
        rmx = fmaxf(rmx, __shfl_xor(rmx, off, 64));
    }
    if (lane == 0) { red3[0][wid] = wmn; red3[1][wid] = rmn; red3[2][wid] = rmx; }
    __syncthreads();                                           // (1)

    {
        float om = -1e30f;
        for (int j = 0; j < wid; ++j) om = fmaxf(om, wtotmax[j]);
        pm[tid] = fmaxf(pmv, om);
    }
    float wmin = red3[0][0], rmin = red3[1][0], rmax = red3[2][0], wmax = wtotmax[0];
    #pragma unroll
    for (int j = 1; j < 8; ++j) {
        wmin = fminf(wmin, red3[0][j]);
        rmin = fminf(rmin, red3[1][j]);
        rmax = fmaxf(rmax, red3[2][j]);
        wmax = fmaxf(wmax, wtotmax[j]);
    }

    // ---- histograms ----
    const float wscale = 255.0f / fmaxf(wmax - wmin, 1e-30f);
    int wk = (int)((wv - wmin) * wscale);
    wk = wk < 0 ? 0 : (wk > 255 ? 255 : wk);
    atomicAdd(&cnt[wk], 1);
    const float rscale = 255.0f / fmaxf(rmax - rmin, 1e-30f);
    int rk;
    { int kv = (int)((rv - rmin) * rscale); kv = kv < 0 ? 0 : (kv > 255 ? 255 : kv); rk = 255 - kv; }
    atomicAdd(&rcnt[rk], 1);
    atomicMax(&rbmax[rk], __float_as_int(rv));                 // rv > 0
    __syncthreads();                                           // (2)

    // ---- both 256-prefix-sums concurrently: waves 0-3 cnt, waves 4-7 rcnt ----
    int myc = (tid < 256) ? cnt[tid] : rcnt[tid - 256];
    int incl = myc;
    #pragma unroll
    for (int off = 1; off < 64; off <<= 1) {
        int o = __shfl_up(incl, off, 64);
        if (lane >= off) incl += o;
    }
    if (lane == 63) { if (wid < 4) ctot[wid] = incl; else rtot[wid - 4] = incl; }
    __syncthreads();                                           // (3)
    if (tid < 256) {
        int eo = 0;
        for (int j = 0; j < wid; ++j) eo += ctot[j];
        cbase[tid] = eo + incl - myc;
    } else {
        int eo = 0, w2 = wid - 4;
        for (int j = 0; j < w2; ++j) eo += rtot[j];
        rbase[tid - 256] = eo + incl - myc;
    }
    __syncthreads();                                           // (4)

    // ---- scatter (bucket-ordered) ----
    { int p1 = cbase[wk] + atomicAdd(&cslot[wk], 1); wsrt[p1] = wv; }
    { int p2 = rbase[rk] + atomicAdd(&rslot[rk], 1);
      srx_r[p2] = rv; srx_n[p2] = tid; srx_u[p2] = __int_as_float(rbmax[rk]); }
    __syncthreads();                                           // (5)

    // ---- per-bucket f64 sums + 256-prefix (waves 0-3) ----
    double bincl = 0.0, mysum = 0.0;
    if (tid < 256) {
        int st = cbase[tid], e = st + cnt[tid];
        for (int i = st; i < e; ++i) mysum += (double)wsrt[i];
        bincl = mysum;
        #pragma unroll
        for (int off = 1; off < 64; off <<= 1) {
            double o = __shfl_up(bincl, off, 64);
            if (lane >= off) bincl += o;
        }
        if (lane == 63) btot[wid] = bincl;
    }
    __syncthreads();                                           // (6)
    if (tid < 256) {
        double eo = 0.0;
        for (int j = 0; j < wid; ++j) eo += btot[j];
        bsumI[tid] = eo + bincl;
    }
    __syncthreads();                                           // (7)

    if (tid < 256) {
        // ==== phase C: ind_w scan, descending-rel buckets (waves 0-3) ====
        const int b = tid;
        float bv = -1.0f; int bi = 0;
        for (int i = 0; i < 512; ++i) {
            float u = srx_u[i];                      // non-increasing bound
            if (__ballot(u >= bv) == 0ULL) break;
            float r = srx_r[i];
            int   n = srx_n[i];
            float xv = xT[n * B + b];                // coalesced
            float v = fminf(xv, r);
            if (v > bv || (v == bv && n < bi)) { bv = v; bi = n; }
        }
        out[BM + b * M + m] = fminf(x[b * N + bi], worig[bi]);   // chosen_w
    } else {
        // ==== phase D: rel_w CDF + ind_x (waves 4-7) ====
        const int b = tid - 256;
        const float tbm = tT[m * B + b];
        float btf = (tbm - wmin) * wscale;
        int kk; double S;
        if (btf < 0.0f) { kk = 0; S = 0.0; }
        else {
            int bt = (int)btf; bt = bt > 255 ? 255 : bt;
            kk = cbase[bt];
            S = (bt > 0) ? bsumI[bt - 1] : 0.0;
            int e = cbase[bt] + cnt[bt];
            for (int i = cbase[bt]; i < e; ++i) {
                float v = wsrt[i];
                if (v < tbm) { ++kk; S += (double)v; }
            }
        }
        double rw = S + (double)tbm * (double)(512 - kk);
        float c = (float)rw / sum_w[m];
        float tgt = fminf(c, pm[511]);
        int lo = 0, hi = 511;
        while (lo < hi) { int mid = (lo + hi) >> 1; if (pm[mid] >= tgt) hi = mid; else lo = mid + 1; }
        const int ind = lo;
        out[b * M + m] = fminf(x[b * N + ind], worig[ind]);      // chosen_x
    }
}

extern "C" void kernel_launch(void* const* d_in, const int* in_sizes, int n_in,
                              void* d_out, int out_size, void* d_ws, size_t ws_size,
                              hipStream_t stream) {
    const float* x = (const float*)d_in[0];  // (B, N)
    const float* w = (const float*)d_in[1];  // (N, M)
    const float* t = (const float*)d_in[2];  // (B, M)
    float* out = (float*)d_out;

    float* ws = (float*)d_ws;
    float* xT    = ws;                 // 131072
    float* wT    = ws + 131072;        // 262144
    float* tT    = ws + 393216;        // 131072
    float* sum_x = ws + 524288;        // 512
    float* sum_w = ws + 524800;        // 512
    float* px    = ws + 525312;        // 4*NM = 1048576  (~6.3 MB total)

    k_a  <<<644, 256, 0, stream>>>(x, w, t, xT, wT, tT, sum_x, sum_w, px);
    k_col<<<512, 512, 0, stream>>>(x, xT, wT, tT, px, sum_x, sum_w, out);
}